// Round 12
// baseline (343.084 us; speedup 1.0000x reference)
//
#include <hip/hip_runtime.h>
#include <hip/hip_bf16.h>

#define NB 32
#define NS 2048
#define NDD 1024
#define NDE 1024
#define NDA 1024
#define NEGV (-1000000000.0f)

typedef __attribute__((ext_vector_type(8))) __bf16 bf16x8;
typedef __attribute__((ext_vector_type(4))) float f32x4;

__device__ __forceinline__ float fast_tanh(float x) {
    x = fminf(10.0f, fmaxf(-10.0f, x));
    float e = __expf(2.0f * x);
    return __fdividef(e - 1.0f, e + 1.0f);
}

__device__ __forceinline__ float bfu2f(unsigned short v) {
    union { unsigned u; float f; } c; c.u = (unsigned)v << 16; return c.f;
}

// ---------------- We (f32) -> bf16 ----------------
__global__ void prep_we(const float* __restrict__ Wc, __bf16* __restrict__ We) {
    int f = blockIdx.x * 256 + threadIdx.x;
    int a  = f >> 8;
    int k4 = f & 255;
    float4 v = *reinterpret_cast<const float4*>(Wc + (size_t)a * (NDD + NDE) + NDD + k4 * 4);
    union { __bf16 h[4]; uint2 u; } pk;
    pk.h[0] = (__bf16)v.x; pk.h[1] = (__bf16)v.y;
    pk.h[2] = (__bf16)v.z; pk.h[3] = (__bf16)v.w;
    *reinterpret_cast<uint2*>(We + (size_t)a * NDE + k4 * 4) = pk.u;
}

// ---------------- E (f32) -> bf16, nontemporal f32 reads ----------------
__global__ void prep_e(const float* __restrict__ E, __bf16* __restrict__ Eb) {
    size_t i = ((size_t)blockIdx.x * 256 + threadIdx.x) * 8;
    f32x4 x = __builtin_nontemporal_load(reinterpret_cast<const f32x4*>(E + i));
    f32x4 y = __builtin_nontemporal_load(reinterpret_cast<const f32x4*>(E + i + 4));
    union { __bf16 h[8]; uint4 u; } pk;
    pk.h[0] = (__bf16)x[0]; pk.h[1] = (__bf16)x[1]; pk.h[2] = (__bf16)x[2]; pk.h[3] = (__bf16)x[3];
    pk.h[4] = (__bf16)y[0]; pk.h[5] = (__bf16)y[1]; pk.h[6] = (__bf16)y[2]; pk.h[7] = (__bf16)y[3];
    *reinterpret_cast<uint4*>(Eb + i) = pk.u;
}

// ---------------- q_proj = query @ Wq^T (f32, exact) ----------------
__global__ void qproj_kernel(const float* __restrict__ q, const float* __restrict__ Wc,
                             float* __restrict__ qp) {
    __shared__ float qs[NDD];
    int b = blockIdx.y;
    int a = blockIdx.x * 256 + threadIdx.x;
    float4 qv = *reinterpret_cast<const float4*>(q + (size_t)b * NDD + threadIdx.x * 4);
    *reinterpret_cast<float4*>(qs + threadIdx.x * 4) = qv;
    __syncthreads();
    const float* wrow = Wc + (size_t)a * (NDD + NDE);
    float acc = 0.f;
#pragma unroll 4
    for (int k4 = 0; k4 < 256; ++k4) {
        float4 w = *reinterpret_cast<const float4*>(wrow + k4 * 4);
        acc += qs[k4*4+0] * w.x + qs[k4*4+1] * w.y + qs[k4*4+2] * w.z + qs[k4*4+3] * w.w;
    }
    qp[(size_t)b * NDA + a] = acc;
}

// ---------------- 256x128 block / BK=32 / 4 waves (2x2) of 128x64, 2 blocks/CU ----------------
// R7's proven m97 schedule (gload_lds w16, involution swizzle, one barrier/tile) with
// a 2x bigger wave tile (128x64: 8 mf x 4 nf) and 48 KB LDS so TWO blocks co-reside
// per CU (inter-block TLP hides barrier drains — the m114 mechanism R9-R11 lacked).
__global__ __launch_bounds__(256, 2) void score256(
    const __bf16* __restrict__ Eb, const __bf16* __restrict__ We,
    const float* __restrict__ qp, const float* __restrict__ Vv,
    float* __restrict__ sp) {
    __shared__ __align__(16) __bf16 As[2][256 * 32];   // 16 KB each
    __shared__ __align__(16) __bf16 Bs[2][128 * 32];   // 8 KB each

    const int tid  = threadIdx.x;
    const int lane = tid & 63;
    const int l15  = lane & 15;
    const int h    = lane >> 4;          // 0..3 (k-slot)
    const int wid  = tid >> 6;           // 0..3
    const int wr   = wid >> 1;           // 0..1 (row half, 128 rows)
    const int wc   = wid & 1;            // 0..1 (col half, 64 cols)

    const int bid = blockIdx.x;          // grid 2048
    const int xcd = bid & 7;
    const int j   = bid >> 3;            // 0..255
    const int m   = xcd * 32 + (j >> 3); // 0..255
    const int n   = j & 7;               // 0..7
    const int row0  = m * 256;
    const int ncol0 = n * 128;
    const int b     = m >> 3;

    f32x4 acc[8][4];
#pragma unroll
    for (int mf = 0; mf < 8; ++mf)
#pragma unroll
        for (int nf = 0; nf < 4; ++nf)
            acc[mf][nf] = (f32x4){0.f, 0.f, 0.f, 0.f};

    // staging source offsets (pre-inverse-swizzled, 4-slot involution sl ^= (r>>1)&3)
    int offE[4], offW[2];
#pragma unroll
    for (int i = 0; i < 4; ++i) {
        int chunk = i * 256 + tid;
        int r  = chunk >> 2;
        int sg = (chunk & 3) ^ ((r >> 1) & 3);
        offE[i] = (row0 + r) * 1024 + sg * 8;
    }
#pragma unroll
    for (int i = 0; i < 2; ++i) {
        int chunk = i * 256 + tid;
        int r  = chunk >> 2;
        int sg = (chunk & 3) ^ ((r >> 1) & 3);
        offW[i] = (ncol0 + r) * 1024 + sg * 8;
    }

    // frag read byte offsets within [.][32] buffers (row = 64 B)
    int aoff[8], boff[4];
#pragma unroll
    for (int mf = 0; mf < 8; ++mf) {
        int r = wr * 128 + mf * 16 + l15;
        aoff[mf] = r * 64 + ((h ^ ((r >> 1) & 3)) << 4);
    }
#pragma unroll
    for (int nf = 0; nf < 4; ++nf) {
        int r = wc * 64 + nf * 16 + l15;
        boff[nf] = r * 64 + ((h ^ ((r >> 1) & 3)) << 4);
    }

#define STAGE(buf, kc)                                                                  \
    {                                                                                   \
        _Pragma("unroll")                                                               \
        for (int i = 0; i < 4; ++i)                                                     \
            __builtin_amdgcn_global_load_lds(                                           \
                (const __attribute__((address_space(1))) unsigned*)(Eb + offE[i] + (kc)),\
                (__attribute__((address_space(3))) unsigned*)((char*)&As[buf][0] + i * 4096 + wid * 1024), \
                16, 0, 0);                                                              \
        _Pragma("unroll")                                                               \
        for (int i = 0; i < 2; ++i)                                                     \
            __builtin_amdgcn_global_load_lds(                                           \
                (const __attribute__((address_space(1))) unsigned*)(We + offW[i] + (kc)),\
                (__attribute__((address_space(3))) unsigned*)((char*)&Bs[buf][0] + i * 4096 + wid * 1024), \
                16, 0, 0);                                                              \
    }

    STAGE(0, 0)
    __syncthreads();

    for (int it = 0; it < 32; ++it) {
        const int cur = it & 1;
        if (it < 31) STAGE(cur ^ 1, (it + 1) * 32)
        const char* Ab = (const char*)&As[cur][0];
        const char* Bb = (const char*)&Bs[cur][0];
        bf16x8 bfr[4], afr[8];
#pragma unroll
        for (int nf = 0; nf < 4; ++nf)
            bfr[nf] = *reinterpret_cast<const bf16x8*>(Bb + boff[nf]);
#pragma unroll
        for (int mf = 0; mf < 8; ++mf)
            afr[mf] = *reinterpret_cast<const bf16x8*>(Ab + aoff[mf]);
#pragma unroll
        for (int mf = 0; mf < 8; ++mf)
#pragma unroll
            for (int nf = 0; nf < 4; ++nf)
                acc[mf][nf] = __builtin_amdgcn_mfma_f32_16x16x32_bf16(afr[mf], bfr[nf], acc[mf][nf], 0, 0, 0);
        __syncthreads();
    }

    // ---- epilogue: tanh(qp + e_proj) * V, reduce over cols ----
    float qv[4], vv[4];
#pragma unroll
    for (int nf = 0; nf < 4; ++nf) {
        int col = ncol0 + wc * 64 + nf * 16 + l15;
        qv[nf] = qp[(size_t)b * NDA + col];
        vv[nf] = Vv[col];
    }
    float* ps = reinterpret_cast<float*>(&As[0][0]);   // retired; [256][2] f32
#pragma unroll
    for (int mf = 0; mf < 8; ++mf)
#pragma unroll
        for (int jj = 0; jj < 4; ++jj) {
            float s = 0.f;
#pragma unroll
            for (int nf = 0; nf < 4; ++nf)
                s += fast_tanh(qv[nf] + acc[mf][nf][jj]) * vv[nf];
            s += __shfl_xor(s, 1);
            s += __shfl_xor(s, 2);
            s += __shfl_xor(s, 4);
            s += __shfl_xor(s, 8);
            if (l15 == 0)
                ps[(wr * 128 + mf * 16 + h * 4 + jj) * 2 + wc] = s;
        }
    __syncthreads();
    if (tid < 256)
        sp[(size_t)n * (NB * NS) + row0 + tid] = ps[tid * 2] + ps[tid * 2 + 1];
}

// ---------------- masked softmax over s (sums np partials), per b ----------------
__global__ void softmax_kernel(const float* __restrict__ sp, const int* __restrict__ mask,
                               float* __restrict__ wout, int np) {
    int b = blockIdx.x;
    const int* mrow = mask + (size_t)b * NS;
    float v[8];
    float lmax = -INFINITY;
#pragma unroll
    for (int jj = 0; jj < 8; ++jj) {
        int s = threadIdx.x + 256 * jj;
        float sc = 0.f;
        for (int nn = 0; nn < np; ++nn) sc += sp[(size_t)nn * (NB * NS) + b * NS + s];
        v[jj] = (mrow[s] == 0) ? NEGV : sc;
        lmax = fmaxf(lmax, v[jj]);
    }
#pragma unroll
    for (int mm = 1; mm <= 32; mm <<= 1) lmax = fmaxf(lmax, __shfl_xor(lmax, mm));
    __shared__ float redm[4], reds[4];
    if ((threadIdx.x & 63) == 0) redm[threadIdx.x >> 6] = lmax;
    __syncthreads();
    float bmax = fmaxf(fmaxf(redm[0], redm[1]), fmaxf(redm[2], redm[3]));
    float lsum = 0.f;
#pragma unroll
    for (int jj = 0; jj < 8; ++jj) { v[jj] = __expf(v[jj] - bmax); lsum += v[jj]; }
#pragma unroll
    for (int mm = 1; mm <= 32; mm <<= 1) lsum += __shfl_xor(lsum, mm);
    if ((threadIdx.x & 63) == 0) reds[threadIdx.x >> 6] = lsum;
    __syncthreads();
    float inv = __fdividef(1.0f, reds[0] + reds[1] + reds[2] + reds[3]);
#pragma unroll
    for (int jj = 0; jj < 8; ++jj) wout[(size_t)b * NS + threadIdx.x + 256 * jj] = v[jj] * inv;
}

// ---------------- context = w @ Eb (bf16 E copy, L3-resident) ----------------
__global__ void context_bf16(const __bf16* __restrict__ Eb, const float* __restrict__ w,
                             float* __restrict__ ctx) {
    int b  = blockIdx.x >> 3;
    int dc = blockIdx.x & 7;
    int dg = threadIdx.x & 31;
    int ss = threadIdx.x >> 5;
    const __bf16* base = Eb + (size_t)b * NS * NDE + (size_t)(ss * 256) * NDE + dc * 128 + dg * 4;
    const float* wb = w + (size_t)b * NS + ss * 256;
    float a0 = 0.f, a1 = 0.f, a2 = 0.f, a3 = 0.f;
#pragma unroll 8
    for (int s = 0; s < 256; ++s) {
        float ws = wb[s];
        uint2 u = *reinterpret_cast<const uint2*>(base + (size_t)s * NDE);
        a0 = fmaf(ws, bfu2f((unsigned short)(u.x & 0xffff)), a0);
        a1 = fmaf(ws, bfu2f((unsigned short)(u.x >> 16)), a1);
        a2 = fmaf(ws, bfu2f((unsigned short)(u.y & 0xffff)), a2);
        a3 = fmaf(ws, bfu2f((unsigned short)(u.y >> 16)), a3);
    }
    __shared__ float4 part[256];
    part[threadIdx.x] = make_float4(a0, a1, a2, a3);
    __syncthreads();
    if (threadIdx.x < 32) {
        float4 r = part[threadIdx.x];
#pragma unroll
        for (int k = 1; k < 8; ++k) {
            float4 p = part[threadIdx.x + 32 * k];
            r.x += p.x; r.y += p.y; r.z += p.z; r.w += p.w;
        }
        *reinterpret_cast<float4*>(ctx + (size_t)b * NDD + dc * 128 + threadIdx.x * 4) = r;
    }
}

extern "C" void kernel_launch(void* const* d_in, const int* in_sizes, int n_in,
                              void* d_out, int out_size, void* d_ws, size_t ws_size,
                              hipStream_t stream) {
    const float* query = (const float*)d_in[0];
    const float* enc   = (const float*)d_in[1];
    const int*   mask  = (const int*)d_in[2];
    const float* Wc    = (const float*)d_in[3];
    const float* V     = (const float*)d_in[4];

    float* out = (float*)d_out;
    float* ctx = out;                       // (32,1024)
    float* wts = out + NB * NDD;            // (32,2048)

    const size_t WE_B = (size_t)NDA * NDE * 2;        // 2 MB
    const size_t QP_B = (size_t)NB * NDA * 4;         // 128 KB
    const size_t SP_B = (size_t)8 * NB * NS * 4;      // 2 MB
    char* ws = (char*)d_ws;
    __bf16* We = (__bf16*)ws;
    float*  qp = (float*)(ws + WE_B);
    float*  sp = (float*)(ws + WE_B + QP_B);
    __bf16* Eb = (__bf16*)(ws + WE_B + QP_B + SP_B);

    hipLaunchKernelGGL(prep_we,      dim3(1024),  dim3(256), 0, stream, Wc, We);
    hipLaunchKernelGGL(qproj_kernel, dim3(4, NB), dim3(256), 0, stream, query, Wc, qp);
    hipLaunchKernelGGL(prep_e,       dim3(32768), dim3(256), 0, stream, enc, Eb);
    hipLaunchKernelGGL(score256,     dim3(2048),  dim3(256), 0, stream, Eb, We, qp, V, sp);
    hipLaunchKernelGGL(softmax_kernel, dim3(NB),  dim3(256), 0, stream, sp, mask, wts, 8);
    hipLaunchKernelGGL(context_bf16, dim3(256),   dim3(256), 0, stream, Eb, wts, ctx);
}

// Round 13
// 295.351 us; speedup vs baseline: 1.1616x; 1.1616x over previous
//
#include <hip/hip_runtime.h>
#include <hip/hip_bf16.h>

#define NB 32
#define NS 2048
#define NDD 1024
#define NDE 1024
#define NDA 1024
#define NEGV (-1000000000.0f)

typedef __attribute__((ext_vector_type(8))) __bf16 bf16x8;
typedef __attribute__((ext_vector_type(4))) float f32x4;

__device__ __forceinline__ float fast_tanh(float x) {
    x = fminf(10.0f, fmaxf(-10.0f, x));
    float e = __expf(2.0f * x);
    return __fdividef(e - 1.0f, e + 1.0f);
}

__device__ __forceinline__ float bfu2f(unsigned short v) {
    union { unsigned u; float f; } c; c.u = (unsigned)v << 16; return c.f;
}

// ---------------- We (f32) -> bf16 ----------------
__global__ void prep_we(const float* __restrict__ Wc, __bf16* __restrict__ We) {
    int f = blockIdx.x * 256 + threadIdx.x;
    int a  = f >> 8;
    int k4 = f & 255;
    float4 v = *reinterpret_cast<const float4*>(Wc + (size_t)a * (NDD + NDE) + NDD + k4 * 4);
    union { __bf16 h[4]; uint2 u; } pk;
    pk.h[0] = (__bf16)v.x; pk.h[1] = (__bf16)v.y;
    pk.h[2] = (__bf16)v.z; pk.h[3] = (__bf16)v.w;
    *reinterpret_cast<uint2*>(We + (size_t)a * NDE + k4 * 4) = pk.u;
}

// ---------------- E (f32) -> bf16, nontemporal f32 reads ----------------
__global__ void prep_e(const float* __restrict__ E, __bf16* __restrict__ Eb) {
    size_t i = ((size_t)blockIdx.x * 256 + threadIdx.x) * 8;
    f32x4 x = __builtin_nontemporal_load(reinterpret_cast<const f32x4*>(E + i));
    f32x4 y = __builtin_nontemporal_load(reinterpret_cast<const f32x4*>(E + i + 4));
    union { __bf16 h[8]; uint4 u; } pk;
    pk.h[0] = (__bf16)x[0]; pk.h[1] = (__bf16)x[1]; pk.h[2] = (__bf16)x[2]; pk.h[3] = (__bf16)x[3];
    pk.h[4] = (__bf16)y[0]; pk.h[5] = (__bf16)y[1]; pk.h[6] = (__bf16)y[2]; pk.h[7] = (__bf16)y[3];
    *reinterpret_cast<uint4*>(Eb + i) = pk.u;
}

// ---------------- q_proj = query @ Wq^T (f32, exact) ----------------
__global__ void qproj_kernel(const float* __restrict__ q, const float* __restrict__ Wc,
                             float* __restrict__ qp) {
    __shared__ float qs[NDD];
    int b = blockIdx.y;
    int a = blockIdx.x * 256 + threadIdx.x;
    float4 qv = *reinterpret_cast<const float4*>(q + (size_t)b * NDD + threadIdx.x * 4);
    *reinterpret_cast<float4*>(qs + threadIdx.x * 4) = qv;
    __syncthreads();
    const float* wrow = Wc + (size_t)a * (NDD + NDE);
    float acc = 0.f;
#pragma unroll 4
    for (int k4 = 0; k4 < 256; ++k4) {
        float4 w = *reinterpret_cast<const float4*>(wrow + k4 * 4);
        acc += qs[k4*4+0] * w.x + qs[k4*4+1] * w.y + qs[k4*4+2] * w.z + qs[k4*4+3] * w.w;
    }
    qp[(size_t)b * NDA + a] = acc;
}

// ---------------- 256x256 / BK=64 / 8-wave score GEMM, single-barrier m97 schedule ----------------
// (R9 configuration — best measured: 207 µs, MfmaUtil 27%, 0 bank conflicts.)
// 512 thr = 8 waves (2M x 4N); per-wave C = 128x64 (8 mf x 4 nf).
// LDS 128 KB: A[2][256][64] + B[2][256][64] bf16, 8-slot involution swizzle (slot ^= r&7).
// Per K-tile: issue 8 next-tile global_load_lds, 24 ds_read_b128 + 64 MFMA straight-line,
// ONE __syncthreads. qp/Vv loads hoisted into the prologue (fills stage-0 latency).
__global__ __launch_bounds__(512, 2) void score256(
    const __bf16* __restrict__ Eb, const __bf16* __restrict__ We,
    const float* __restrict__ qp, const float* __restrict__ Vv,
    float* __restrict__ sp) {
    __shared__ __align__(16) __bf16 As[2][256 * 64];   // 32 KB each
    __shared__ __align__(16) __bf16 Bs[2][256 * 64];

    const int tid  = threadIdx.x;
    const int lane = tid & 63;
    const int l15  = lane & 15;
    const int h    = lane >> 4;          // 0..3
    const int wid  = tid >> 6;           // 0..7
    const int wr   = wid >> 2;           // 0..1 (row half, 128 rows)
    const int wc   = wid & 3;            // 0..3 (col quarter, 64 cols)

    const int bid = blockIdx.x;
    const int xcd = bid & 7;
    const int j   = bid >> 3;            // 0..127
    const int m   = xcd * 32 + (j >> 2); // 0..255
    const int n   = j & 3;               // 0..3
    const int row0  = m * 256;
    const int ncol0 = n * 256;
    const int b     = m >> 3;

    f32x4 acc[8][4];
#pragma unroll
    for (int mf = 0; mf < 8; ++mf)
#pragma unroll
        for (int nf = 0; nf < 4; ++nf)
            acc[mf][nf] = (f32x4){0.f, 0.f, 0.f, 0.f};

    // staging source offsets (pre-inverse-swizzled), elements
    int offE[4], offW[4];
#pragma unroll
    for (int i = 0; i < 4; ++i) {
        int rr = i * 64 + (tid >> 3);
        int sg = (tid & 7) ^ (rr & 7);
        offE[i] = (row0  + rr) * 1024 + sg * 8;
        offW[i] = (ncol0 + rr) * 1024 + sg * 8;
    }

    // frag read byte offsets (ks=0); ks=1 = ^64
    const int slot0 = ((h ^ (l15 & 7)) * 16);
    const int aoffl = (wr * 128 + l15) * 128 + slot0;
    const int boffl = (wc * 64  + l15) * 128 + slot0;

#define STAGE8(abuf, bbuf, kc)                                                          \
    {                                                                                   \
        _Pragma("unroll")                                                               \
        for (int i = 0; i < 4; ++i)                                                     \
            __builtin_amdgcn_global_load_lds(                                           \
                (const __attribute__((address_space(1))) unsigned*)(Eb + offE[i] + (kc)),\
                (__attribute__((address_space(3))) unsigned*)((char*)(abuf) + i * 8192 + wid * 1024), \
                16, 0, 0);                                                              \
        _Pragma("unroll")                                                               \
        for (int i = 0; i < 4; ++i)                                                     \
            __builtin_amdgcn_global_load_lds(                                           \
                (const __attribute__((address_space(1))) unsigned*)(We + offW[i] + (kc)),\
                (__attribute__((address_space(3))) unsigned*)((char*)(bbuf) + i * 8192 + wid * 1024), \
                16, 0, 0);                                                              \
    }

    // prologue: stage tile 0; hoist qp/Vv loads under the stage latency
    STAGE8(&As[0][0], &Bs[0][0], 0)
    float qv[4], vv[4];
#pragma unroll
    for (int nf = 0; nf < 4; ++nf) {
        int col = ncol0 + wc * 64 + nf * 16 + l15;
        qv[nf] = qp[(size_t)b * NDA + col];
        vv[nf] = Vv[col];
    }
    __syncthreads();

    for (int T = 0; T < 16; ++T) {
        const int cur = T & 1;
        const char* Ab = (const char*)&As[cur][0];
        const char* Bb = (const char*)&Bs[cur][0];
        if (T < 15) STAGE8(&As[cur ^ 1][0], &Bs[cur ^ 1][0], (T + 1) * 64)

        bf16x8 bfr[4][2], afr[4][2];
#pragma unroll
        for (int nf = 0; nf < 4; ++nf) {
            bfr[nf][0] = *reinterpret_cast<const bf16x8*>(Bb + (boffl + nf * 2048));
            bfr[nf][1] = *reinterpret_cast<const bf16x8*>(Bb + ((boffl + nf * 2048) ^ 64));
        }
#pragma unroll
        for (int mi = 0; mi < 4; ++mi) {
            afr[mi][0] = *reinterpret_cast<const bf16x8*>(Ab + (aoffl + mi * 2048));
            afr[mi][1] = *reinterpret_cast<const bf16x8*>(Ab + ((aoffl + mi * 2048) ^ 64));
        }
        __builtin_amdgcn_s_setprio(1);
#pragma unroll
        for (int ks = 0; ks < 2; ++ks)
#pragma unroll
            for (int mi = 0; mi < 4; ++mi)
#pragma unroll
                for (int nf = 0; nf < 4; ++nf)
                    acc[mi][nf] = __builtin_amdgcn_mfma_f32_16x16x32_bf16(afr[mi][ks], bfr[nf][ks], acc[mi][nf], 0, 0, 0);
        __builtin_amdgcn_s_setprio(0);
#pragma unroll
        for (int mi = 0; mi < 4; ++mi) {
            afr[mi][0] = *reinterpret_cast<const bf16x8*>(Ab + (aoffl + (4 + mi) * 2048));
            afr[mi][1] = *reinterpret_cast<const bf16x8*>(Ab + ((aoffl + (4 + mi) * 2048) ^ 64));
        }
        __builtin_amdgcn_s_setprio(1);
#pragma unroll
        for (int ks = 0; ks < 2; ++ks)
#pragma unroll
            for (int mi = 0; mi < 4; ++mi)
#pragma unroll
                for (int nf = 0; nf < 4; ++nf)
                    acc[4 + mi][nf] = __builtin_amdgcn_mfma_f32_16x16x32_bf16(afr[mi][ks], bfr[nf][ks], acc[4 + mi][nf], 0, 0, 0);
        __builtin_amdgcn_s_setprio(0);
        __syncthreads();
    }

    // ---- epilogue: tanh(qp + e_proj) * V, reduce over cols ----
    float* ps2 = reinterpret_cast<float*>(&As[0][0]);  // retired; [256][4] f32
#pragma unroll
    for (int mf = 0; mf < 8; ++mf)
#pragma unroll
        for (int jj = 0; jj < 4; ++jj) {
            float s = 0.f;
#pragma unroll
            for (int nf = 0; nf < 4; ++nf)
                s += fast_tanh(qv[nf] + acc[mf][nf][jj]) * vv[nf];
            s += __shfl_xor(s, 1);
            s += __shfl_xor(s, 2);
            s += __shfl_xor(s, 4);
            s += __shfl_xor(s, 8);
            if (l15 == 0)
                ps2[(wr * 128 + mf * 16 + h * 4 + jj) * 4 + wc] = s;
        }
    __syncthreads();
    if (tid < 256)
        sp[(size_t)n * (NB * NS) + row0 + tid] =
            ps2[tid * 4] + ps2[tid * 4 + 1] + ps2[tid * 4 + 2] + ps2[tid * 4 + 3];
}

// ---------------- masked softmax over s (sums np partials), per b ----------------
__global__ void softmax_kernel(const float* __restrict__ sp, const int* __restrict__ mask,
                               float* __restrict__ wout, int np) {
    int b = blockIdx.x;
    const int* mrow = mask + (size_t)b * NS;
    float v[8];
    float lmax = -INFINITY;
#pragma unroll
    for (int jj = 0; jj < 8; ++jj) {
        int s = threadIdx.x + 256 * jj;
        float sc = 0.f;
        for (int nn = 0; nn < np; ++nn) sc += sp[(size_t)nn * (NB * NS) + b * NS + s];
        v[jj] = (mrow[s] == 0) ? NEGV : sc;
        lmax = fmaxf(lmax, v[jj]);
    }
#pragma unroll
    for (int mm = 1; mm <= 32; mm <<= 1) lmax = fmaxf(lmax, __shfl_xor(lmax, mm));
    __shared__ float redm[4], reds[4];
    if ((threadIdx.x & 63) == 0) redm[threadIdx.x >> 6] = lmax;
    __syncthreads();
    float bmax = fmaxf(fmaxf(redm[0], redm[1]), fmaxf(redm[2], redm[3]));
    float lsum = 0.f;
#pragma unroll
    for (int jj = 0; jj < 8; ++jj) { v[jj] = __expf(v[jj] - bmax); lsum += v[jj]; }
#pragma unroll
    for (int mm = 1; mm <= 32; mm <<= 1) lsum += __shfl_xor(lsum, mm);
    if ((threadIdx.x & 63) == 0) reds[threadIdx.x >> 6] = lsum;
    __syncthreads();
    float inv = __fdividef(1.0f, reds[0] + reds[1] + reds[2] + reds[3]);
#pragma unroll
    for (int jj = 0; jj < 8; ++jj) wout[(size_t)b * NS + threadIdx.x + 256 * jj] = v[jj] * inv;
}

// ---------------- context = w @ Eb (bf16 E copy, L3-resident) ----------------
__global__ void context_bf16(const __bf16* __restrict__ Eb, const float* __restrict__ w,
                             float* __restrict__ ctx) {
    int b  = blockIdx.x >> 3;
    int dc = blockIdx.x & 7;
    int dg = threadIdx.x & 31;
    int ss = threadIdx.x >> 5;
    const __bf16* base = Eb + (size_t)b * NS * NDE + (size_t)(ss * 256) * NDE + dc * 128 + dg * 4;
    const float* wb = w + (size_t)b * NS + ss * 256;
    float a0 = 0.f, a1 = 0.f, a2 = 0.f, a3 = 0.f;
#pragma unroll 8
    for (int s = 0; s < 256; ++s) {
        float ws = wb[s];
        uint2 u = *reinterpret_cast<const uint2*>(base + (size_t)s * NDE);
        a0 = fmaf(ws, bfu2f((unsigned short)(u.x & 0xffff)), a0);
        a1 = fmaf(ws, bfu2f((unsigned short)(u.x >> 16)), a1);
        a2 = fmaf(ws, bfu2f((unsigned short)(u.y & 0xffff)), a2);
        a3 = fmaf(ws, bfu2f((unsigned short)(u.y >> 16)), a3);
    }
    __shared__ float4 part[256];
    part[threadIdx.x] = make_float4(a0, a1, a2, a3);
    __syncthreads();
    if (threadIdx.x < 32) {
        float4 r = part[threadIdx.x];
#pragma unroll
        for (int k = 1; k < 8; ++k) {
            float4 p = part[threadIdx.x + 32 * k];
            r.x += p.x; r.y += p.y; r.z += p.z; r.w += p.w;
        }
        *reinterpret_cast<float4*>(ctx + (size_t)b * NDD + dc * 128 + threadIdx.x * 4) = r;
    }
}

extern "C" void kernel_launch(void* const* d_in, const int* in_sizes, int n_in,
                              void* d_out, int out_size, void* d_ws, size_t ws_size,
                              hipStream_t stream) {
    const float* query = (const float*)d_in[0];
    const float* enc   = (const float*)d_in[1];
    const int*   mask  = (const int*)d_in[2];
    const float* Wc    = (const float*)d_in[3];
    const float* V     = (const float*)d_in[4];

    float* out = (float*)d_out;
    float* ctx = out;                       // (32,1024)
    float* wts = out + NB * NDD;            // (32,2048)

    const size_t WE_B = (size_t)NDA * NDE * 2;        // 2 MB
    const size_t QP_B = (size_t)NB * NDA * 4;         // 128 KB
    const size_t SP_B = (size_t)8 * NB * NS * 4;      // 2 MB
    char* ws = (char*)d_ws;
    __bf16* We = (__bf16*)ws;
    float*  qp = (float*)(ws + WE_B);
    float*  sp = (float*)(ws + WE_B + QP_B);
    __bf16* Eb = (__bf16*)(ws + WE_B + QP_B + SP_B);

    hipLaunchKernelGGL(prep_we,      dim3(1024),  dim3(256), 0, stream, Wc, We);
    hipLaunchKernelGGL(qproj_kernel, dim3(4, NB), dim3(256), 0, stream, query, Wc, qp);
    hipLaunchKernelGGL(prep_e,       dim3(32768), dim3(256), 0, stream, enc, Eb);
    hipLaunchKernelGGL(score256,     dim3(1024),  dim3(512), 0, stream, Eb, We, qp, V, sp);
    hipLaunchKernelGGL(softmax_kernel, dim3(NB),  dim3(256), 0, stream, sp, mask, wts, 4);
    hipLaunchKernelGGL(context_bf16, dim3(256),   dim3(256), 0, stream, Eb, wts, ctx);
}

// Round 14
// 289.443 us; speedup vs baseline: 1.1853x; 1.0204x over previous
//
#include <hip/hip_runtime.h>
#include <hip/hip_bf16.h>

#define NB 32
#define NS 2048
#define NDD 1024
#define NDE 1024
#define NDA 1024
#define NEGV (-1000000000.0f)

typedef __attribute__((ext_vector_type(8))) __bf16 bf16x8;
typedef __attribute__((ext_vector_type(4))) float f32x4;

__device__ __forceinline__ float fast_tanh(float x) {
    x = fminf(10.0f, fmaxf(-10.0f, x));
    float e = __expf(2.0f * x);
    return __fdividef(e - 1.0f, e + 1.0f);
}

__device__ __forceinline__ float bfu2f(unsigned short v) {
    union { unsigned u; float f; } c; c.u = (unsigned)v << 16; return c.f;
}

// ---------------- We (f32) -> bf16 ----------------
__global__ void prep_we(const float* __restrict__ Wc, __bf16* __restrict__ We) {
    int f = blockIdx.x * 256 + threadIdx.x;
    int a  = f >> 8;
    int k4 = f & 255;
    float4 v = *reinterpret_cast<const float4*>(Wc + (size_t)a * (NDD + NDE) + NDD + k4 * 4);
    union { __bf16 h[4]; uint2 u; } pk;
    pk.h[0] = (__bf16)v.x; pk.h[1] = (__bf16)v.y;
    pk.h[2] = (__bf16)v.z; pk.h[3] = (__bf16)v.w;
    *reinterpret_cast<uint2*>(We + (size_t)a * NDE + k4 * 4) = pk.u;
}

// ---------------- E (f32) -> bf16, nontemporal f32 reads ----------------
__global__ void prep_e(const float* __restrict__ E, __bf16* __restrict__ Eb) {
    size_t i = ((size_t)blockIdx.x * 256 + threadIdx.x) * 8;
    f32x4 x = __builtin_nontemporal_load(reinterpret_cast<const f32x4*>(E + i));
    f32x4 y = __builtin_nontemporal_load(reinterpret_cast<const f32x4*>(E + i + 4));
    union { __bf16 h[8]; uint4 u; } pk;
    pk.h[0] = (__bf16)x[0]; pk.h[1] = (__bf16)x[1]; pk.h[2] = (__bf16)x[2]; pk.h[3] = (__bf16)x[3];
    pk.h[4] = (__bf16)y[0]; pk.h[5] = (__bf16)y[1]; pk.h[6] = (__bf16)y[2]; pk.h[7] = (__bf16)y[3];
    *reinterpret_cast<uint4*>(Eb + i) = pk.u;
}

// ---------------- q_proj = query @ Wq^T (f32, exact) ----------------
__global__ void qproj_kernel(const float* __restrict__ q, const float* __restrict__ Wc,
                             float* __restrict__ qp) {
    __shared__ float qs[NDD];
    int b = blockIdx.y;
    int a = blockIdx.x * 256 + threadIdx.x;
    float4 qv = *reinterpret_cast<const float4*>(q + (size_t)b * NDD + threadIdx.x * 4);
    *reinterpret_cast<float4*>(qs + threadIdx.x * 4) = qv;
    __syncthreads();
    const float* wrow = Wc + (size_t)a * (NDD + NDE);
    float acc = 0.f;
#pragma unroll 4
    for (int k4 = 0; k4 < 256; ++k4) {
        float4 w = *reinterpret_cast<const float4*>(wrow + k4 * 4);
        acc += qs[k4*4+0] * w.x + qs[k4*4+1] * w.y + qs[k4*4+2] * w.z + qs[k4*4+3] * w.w;
    }
    qp[(size_t)b * NDA + a] = acc;
}

// ---------------- 256x256 / BK=64 / 16-wave (1024-thr) score GEMM ----------------
// Same geometry/swizzle/schedule as R9 but 16 waves (4M x 4N) of 64x64 tiles ->
// 4 waves/SIMD inside the block (vs 2), doubling latency absorption (m114).
// acc[4][4] = 64 VGPR; ks-split frag reads keep live frags at 8 -> ~116 VGPR total.
// LDS 128 KB: A[2][256][64] + B[2][256][64] bf16, 8-slot involution swizzle.
__global__ __launch_bounds__(1024, 1) void score256(
    const __bf16* __restrict__ Eb, const __bf16* __restrict__ We,
    const float* __restrict__ qp, const float* __restrict__ Vv,
    float* __restrict__ sp) {
    __shared__ __align__(16) __bf16 As[2][256 * 64];   // 32 KB each
    __shared__ __align__(16) __bf16 Bs[2][256 * 64];

    const int tid  = threadIdx.x;
    const int lane = tid & 63;
    const int l15  = lane & 15;
    const int h    = lane >> 4;          // 0..3 (k-slot)
    const int wid  = tid >> 6;           // 0..15
    const int wr   = wid >> 2;           // 0..3 (row quarter, 64 rows)
    const int wc   = wid & 3;            // 0..3 (col quarter, 64 cols)

    const int bid = blockIdx.x;
    const int xcd = bid & 7;
    const int j   = bid >> 3;            // 0..127
    const int m   = xcd * 32 + (j >> 2); // 0..255
    const int n   = j & 3;               // 0..3
    const int row0  = m * 256;
    const int ncol0 = n * 256;
    const int b     = m >> 3;

    f32x4 acc[4][4];
#pragma unroll
    for (int mf = 0; mf < 4; ++mf)
#pragma unroll
        for (int nf = 0; nf < 4; ++nf)
            acc[mf][nf] = (f32x4){0.f, 0.f, 0.f, 0.f};

    // staging source offsets (pre-inverse-swizzled): chunk = i*1024 + tid, 16B each
    int offE[2], offW[2];
#pragma unroll
    for (int i = 0; i < 2; ++i) {
        int chunk = i * 1024 + tid;
        int r  = chunk >> 3;             // 0..255
        int sg = (chunk & 7) ^ (r & 7);
        offE[i] = (row0  + r) * 1024 + sg * 8;
        offW[i] = (ncol0 + r) * 1024 + sg * 8;
    }

    // frag read byte offsets (ks=0); ks=1 = ^64
    const int slot0 = ((h ^ (l15 & 7)) * 16);
    const int aoffl = (wr * 64 + l15) * 128 + slot0;
    const int boffl = (wc * 64 + l15) * 128 + slot0;

#define STAGE4(abuf, bbuf, kc)                                                          \
    {                                                                                   \
        _Pragma("unroll")                                                               \
        for (int i = 0; i < 2; ++i)                                                     \
            __builtin_amdgcn_global_load_lds(                                           \
                (const __attribute__((address_space(1))) unsigned*)(Eb + offE[i] + (kc)),\
                (__attribute__((address_space(3))) unsigned*)((char*)(abuf) + i * 16384 + wid * 1024), \
                16, 0, 0);                                                              \
        _Pragma("unroll")                                                               \
        for (int i = 0; i < 2; ++i)                                                     \
            __builtin_amdgcn_global_load_lds(                                           \
                (const __attribute__((address_space(1))) unsigned*)(We + offW[i] + (kc)),\
                (__attribute__((address_space(3))) unsigned*)((char*)(bbuf) + i * 16384 + wid * 1024), \
                16, 0, 0);                                                              \
    }

    // prologue: stage tile 0; hoist qp/Vv loads under the stage latency
    STAGE4(&As[0][0], &Bs[0][0], 0)
    float qv[4], vv[4];
#pragma unroll
    for (int nf = 0; nf < 4; ++nf) {
        int col = ncol0 + wc * 64 + nf * 16 + l15;
        qv[nf] = qp[(size_t)b * NDA + col];
        vv[nf] = Vv[col];
    }
    __syncthreads();

    for (int T = 0; T < 16; ++T) {
        const int cur = T & 1;
        const char* Ab = (const char*)&As[cur][0];
        const char* Bb = (const char*)&Bs[cur][0];
        if (T < 15) STAGE4(&As[cur ^ 1][0], &Bs[cur ^ 1][0], (T + 1) * 64)

#pragma unroll
        for (int ks = 0; ks < 2; ++ks) {
            bf16x8 bfr[4], afr[4];
#pragma unroll
            for (int nf = 0; nf < 4; ++nf)
                bfr[nf] = *reinterpret_cast<const bf16x8*>(Bb + ((boffl + nf * 2048) ^ (ks * 64)));
#pragma unroll
            for (int mf = 0; mf < 4; ++mf)
                afr[mf] = *reinterpret_cast<const bf16x8*>(Ab + ((aoffl + mf * 2048) ^ (ks * 64)));
            __builtin_amdgcn_s_setprio(1);
#pragma unroll
            for (int mf = 0; mf < 4; ++mf)
#pragma unroll
                for (int nf = 0; nf < 4; ++nf)
                    acc[mf][nf] = __builtin_amdgcn_mfma_f32_16x16x32_bf16(afr[mf], bfr[nf], acc[mf][nf], 0, 0, 0);
            __builtin_amdgcn_s_setprio(0);
        }
        __syncthreads();
    }

    // ---- epilogue: tanh(qp + e_proj) * V, reduce over cols ----
    float* ps2 = reinterpret_cast<float*>(&As[0][0]);  // retired; [256][4] f32
#pragma unroll
    for (int mf = 0; mf < 4; ++mf)
#pragma unroll
        for (int jj = 0; jj < 4; ++jj) {
            float s = 0.f;
#pragma unroll
            for (int nf = 0; nf < 4; ++nf)
                s += fast_tanh(qv[nf] + acc[mf][nf][jj]) * vv[nf];
            s += __shfl_xor(s, 1);
            s += __shfl_xor(s, 2);
            s += __shfl_xor(s, 4);
            s += __shfl_xor(s, 8);
            if (l15 == 0)
                ps2[(wr * 64 + mf * 16 + h * 4 + jj) * 4 + wc] = s;
        }
    __syncthreads();
    if (tid < 256)
        sp[(size_t)n * (NB * NS) + row0 + tid] =
            ps2[tid * 4] + ps2[tid * 4 + 1] + ps2[tid * 4 + 2] + ps2[tid * 4 + 3];
}

// ---------------- masked softmax over s (sums np partials), per b ----------------
__global__ void softmax_kernel(const float* __restrict__ sp, const int* __restrict__ mask,
                               float* __restrict__ wout, int np) {
    int b = blockIdx.x;
    const int* mrow = mask + (size_t)b * NS;
    float v[8];
    float lmax = -INFINITY;
#pragma unroll
    for (int jj = 0; jj < 8; ++jj) {
        int s = threadIdx.x + 256 * jj;
        float sc = 0.f;
        for (int nn = 0; nn < np; ++nn) sc += sp[(size_t)nn * (NB * NS) + b * NS + s];
        v[jj] = (mrow[s] == 0) ? NEGV : sc;
        lmax = fmaxf(lmax, v[jj]);
    }
#pragma unroll
    for (int mm = 1; mm <= 32; mm <<= 1) lmax = fmaxf(lmax, __shfl_xor(lmax, mm));
    __shared__ float redm[4], reds[4];
    if ((threadIdx.x & 63) == 0) redm[threadIdx.x >> 6] = lmax;
    __syncthreads();
    float bmax = fmaxf(fmaxf(redm[0], redm[1]), fmaxf(redm[2], redm[3]));
    float lsum = 0.f;
#pragma unroll
    for (int jj = 0; jj < 8; ++jj) { v[jj] = __expf(v[jj] - bmax); lsum += v[jj]; }
#pragma unroll
    for (int mm = 1; mm <= 32; mm <<= 1) lsum += __shfl_xor(lsum, mm);
    if ((threadIdx.x & 63) == 0) reds[threadIdx.x >> 6] = lsum;
    __syncthreads();
    float inv = __fdividef(1.0f, reds[0] + reds[1] + reds[2] + reds[3]);
#pragma unroll
    for (int jj = 0; jj < 8; ++jj) wout[(size_t)b * NS + threadIdx.x + 256 * jj] = v[jj] * inv;
}

// ---------------- context = w @ Eb (bf16 E copy, L3-resident) ----------------
__global__ void context_bf16(const __bf16* __restrict__ Eb, const float* __restrict__ w,
                             float* __restrict__ ctx) {
    int b  = blockIdx.x >> 3;
    int dc = blockIdx.x & 7;
    int dg = threadIdx.x & 31;
    int ss = threadIdx.x >> 5;
    const __bf16* base = Eb + (size_t)b * NS * NDE + (size_t)(ss * 256) * NDE + dc * 128 + dg * 4;
    const float* wb = w + (size_t)b * NS + ss * 256;
    float a0 = 0.f, a1 = 0.f, a2 = 0.f, a3 = 0.f;
#pragma unroll 8
    for (int s = 0; s < 256; ++s) {
        float ws = wb[s];
        uint2 u = *reinterpret_cast<const uint2*>(base + (size_t)s * NDE);
        a0 = fmaf(ws, bfu2f((unsigned short)(u.x & 0xffff)), a0);
        a1 = fmaf(ws, bfu2f((unsigned short)(u.x >> 16)), a1);
        a2 = fmaf(ws, bfu2f((unsigned short)(u.y & 0xffff)), a2);
        a3 = fmaf(ws, bfu2f((unsigned short)(u.y >> 16)), a3);
    }
    __shared__ float4 part[256];
    part[threadIdx.x] = make_float4(a0, a1, a2, a3);
    __syncthreads();
    if (threadIdx.x < 32) {
        float4 r = part[threadIdx.x];
#pragma unroll
        for (int k = 1; k < 8; ++k) {
            float4 p = part[threadIdx.x + 32 * k];
            r.x += p.x; r.y += p.y; r.z += p.z; r.w += p.w;
        }
        *reinterpret_cast<float4*>(ctx + (size_t)b * NDD + dc * 128 + threadIdx.x * 4) = r;
    }
}

extern "C" void kernel_launch(void* const* d_in, const int* in_sizes, int n_in,
                              void* d_out, int out_size, void* d_ws, size_t ws_size,
                              hipStream_t stream) {
    const float* query = (const float*)d_in[0];
    const float* enc   = (const float*)d_in[1];
    const int*   mask  = (const int*)d_in[2];
    const float* Wc    = (const float*)d_in[3];
    const float* V     = (const float*)d_in[4];

    float* out = (float*)d_out;
    float* ctx = out;                       // (32,1024)
    float* wts = out + NB * NDD;            // (32,2048)

    const size_t WE_B = (size_t)NDA * NDE * 2;        // 2 MB
    const size_t QP_B = (size_t)NB * NDA * 4;         // 128 KB
    const size_t SP_B = (size_t)8 * NB * NS * 4;      // 2 MB
    char* ws = (char*)d_ws;
    __bf16* We = (__bf16*)ws;
    float*  qp = (float*)(ws + WE_B);
    float*  sp = (float*)(ws + WE_B + QP_B);
    __bf16* Eb = (__bf16*)(ws + WE_B + QP_B + SP_B);

    hipLaunchKernelGGL(prep_we,      dim3(1024),  dim3(256), 0, stream, Wc, We);
    hipLaunchKernelGGL(qproj_kernel, dim3(4, NB), dim3(256), 0, stream, query, Wc, qp);
    hipLaunchKernelGGL(prep_e,       dim3(32768), dim3(256), 0, stream, enc, Eb);
    hipLaunchKernelGGL(score256,     dim3(1024),  dim3(1024), 0, stream, Eb, We, qp, V, sp);
    hipLaunchKernelGGL(softmax_kernel, dim3(NB),  dim3(256), 0, stream, sp, mask, wts, 4);
    hipLaunchKernelGGL(context_bf16, dim3(256),   dim3(256), 0, stream, Eb, wts, ctx);
}